// Round 9
// baseline (114.764 us; speedup 1.0000x reference)
//
#include <hip/hip_runtime.h>
#include <math.h>

// Problem constants
#define BB    16      // batch
#define CC    64      // channels
#define HW    441     // h*w
#define QP    448     // padded to 28 tiles of 16
#define NCLS  10
#define MM    2205
#define MP    2208    // padded to 138 tiles of 16 = 69 pairs
#define NSPLIT 5      // m-splits: tiles 28,28,28,28,26

typedef _Float16 half8 __attribute__((ext_vector_type(8)));
typedef float   float4_ __attribute__((ext_vector_type(4)));
typedef float   float2_ __attribute__((ext_vector_type(2)));

// s_waitcnt with vmcnt(n), lgkmcnt/expcnt = no-wait (gfx9 encoding)
#define WAIT_VMCNT(n) __builtin_amdgcn_s_waitcnt(0x0F70 | (n))

// async global->LDS 16B per lane; lds dest = wave-uniform base (+lane*16 implicit)
#define GLDS16(g, l) __builtin_amdgcn_global_load_lds(                         \
    (const __attribute__((address_space(1))) unsigned int*)(const void*)(g),   \
    (__attribute__((address_space(3))) unsigned int*)(void*)(l), 16, 0, 0)

// sorted top-2 insert (a0>=a1): 2 ops
__device__ __forceinline__ void ins2(float d, float& a0, float& a1) {
    float n0 = fmaxf(d, a0);
    float n1 = __builtin_amdgcn_fmed3f(d, a0, a1);
    a0 = n0; a1 = n1;
}

// merge two sorted pairs keeping exact top-2: 3 ops
__device__ __forceinline__ void mrgp(float b0, float b1, float& a0, float& a1) {
    float c1 = __builtin_amdgcn_fmed3f(a0, b0, fmaxf(a1, b1));
    a0 = fmaxf(a0, b0);
    a1 = c1;
}

// insert sorted pair (d0>=d1) into sorted triple (a0>=a1>=a2): 5 ops
__device__ __forceinline__ void inspair3(float d0, float d1,
                                         float& a0, float& a1, float& a2) {
    float n0 = fmaxf(a0, d0);
    float n1 = __builtin_amdgcn_fmed3f(d0, a0, a1);
    float n2 = __builtin_amdgcn_fmed3f(d0, a1, a2);
    float m1 = fmaxf(n1, d1);
    float m2 = __builtin_amdgcn_fmed3f(d1, n1, n2);
    a0 = n0; a1 = m1; a2 = m2;
}

// ---- fused prep: normalize queries (linear fp16) + supports (fp16, XOR-swizzled
// piece order within each 128B descriptor), coalesced 4KB block stores ----
__global__ __launch_bounds__(256) void prep(const float* __restrict__ x1,
                                            const float* __restrict__ x2,
                                            _Float16* __restrict__ qn,
                                            _Float16* __restrict__ sn) {
    __shared__ float ssred[256];
    __shared__ half8 obuf[256];     // 32 descriptors x 8 pieces = 4KB
    int tid = threadIdx.x;
    int ml = tid & 31, cg = tid >> 5;     // 32 descriptors x 8 c-groups
    float v[8];
    half8* dstblk;
    int wz;
    if (blockIdx.x < BB * 14) {           // queries: 16 b x 14 p-tiles of 32
        int b = blockIdx.x / 14, pt = blockIdx.x % 14;
        int p = pt * 32 + ml;
        const float* src = x1 + (size_t)b * CC * HW + p;
        bool real = p < HW;
        #pragma unroll
        for (int i = 0; i < 8; ++i) v[i] = real ? src[(size_t)(cg * 8 + i) * HW] : 0.f;
        wz = cg;                                            // linear
        dstblk = (half8*)(qn + ((size_t)(b * QP + pt * 32)) * CC);
    } else {                              // supports: 10 n x 69 m-tiles of 32
        int sb = blockIdx.x - BB * 14;
        int n = sb / 69, mt = sb % 69;
        int m = mt * 32 + ml;
        const float* src = x2 + (size_t)n * CC * MM + m;
        bool real = m < MM;
        #pragma unroll
        for (int i = 0; i < 8; ++i) v[i] = real ? src[(size_t)(cg * 8 + i) * MM] : 0.f;
        wz = cg ^ (ml & 7);                                 // bank-swizzled piece
        dstblk = (half8*)(sn + ((size_t)(n * MP + mt * 32)) * CC);
    }
    float ss = 0.f;
    #pragma unroll
    for (int i = 0; i < 8; ++i) ss += v[i] * v[i];
    ssred[tid] = ss;
    __syncthreads();
    float tot = 0.f;
    #pragma unroll
    for (int j = 0; j < 8; ++j) tot += ssred[j * 32 + ml];
    float inv = 1.f / fmaxf(sqrtf(tot), 1e-12f);
    half8 h;
    #pragma unroll
    for (int i = 0; i < 8; ++i) h[i] = (_Float16)(v[i] * inv);
    obuf[ml * 8 + wz] = h;
    __syncthreads();
    dstblk[tid] = obuf[tid];              // 256 x 16B contiguous
}

// ---- main: stage the whole 28-tile m-split into LDS ONCE (57KB), then
// barrier-free LDS-resident compute. 4 waves x 7 q-tiles (A in regs, 14x B reuse),
// pair-max + top-2/slot, shallow 2-step pair-butterfly epilogue (top-2 per
// 4-col group). R8 lesson: per-chunk __syncthreads drained the prefetch every
// iteration -> 80% stall; staging once removes every in-loop barrier. ----
__global__ __launch_bounds__(256, 2) void img2class_mfma(const _Float16* __restrict__ qn,
                                                         const _Float16* __restrict__ sn,
                                                         float2_* __restrict__ partial) {
    __shared__ half8 ldsv[28 * 16 * 8];   // 57,344 B: 448 descriptors
    _Float16* lds = (_Float16*)ldsv;

    int ms = blockIdx.x % NSPLIT;     // m-split 0..4
    int bn = blockIdx.x / NSPLIT;     // 0..159
    int b = bn / NCLS, n = bn % NCLS;
    int tid  = threadIdx.x;
    int wave = tid >> 6, lane = tid & 63;
    int col  = lane & 15, quad = lane >> 4;

    int npair = (ms < 4) ? 14 : 13;   // tiles = 2*npair

    // stage this split's support rows: wave w copies bytes [w*npair KB, (w+1)*npair KB)
    const char* sbase = (const char*)(sn + (size_t)n * MP * CC)
                        + (size_t)(ms * 28) * 16 * CC * 2;
    {
        const char* g = sbase + wave * npair * 1024 + lane * 16;
        char* l = (char*)ldsv + wave * npair * 1024;
        for (int i = 0; i < npair; ++i)
            GLDS16(g + i * 1024, l + i * 1024);
    }

    // A fragments for 7 q-tiles (wave owns queries wave*112 .. +111)
    half8 A0[7], A1[7];
    const _Float16* abase = qn + ((size_t)(b * QP + wave * 112 + col)) * CC + quad * 8;
    #pragma unroll
    for (int qt = 0; qt < 7; ++qt) {
        A0[qt] = *(const half8*)(abase + qt * 16 * CC);
        A1[qt] = *(const half8*)(abase + qt * 16 * CC + 32);
    }

    float t0[7][4], t1[7][4];
    #pragma unroll
    for (int qt = 0; qt < 7; ++qt)
        #pragma unroll
        for (int r = 0; r < 4; ++r) { t0[qt][r] = -1.0e30f; t1[qt][r] = -1.0e30f; }

    // global tile 137 = split 4, pair 12, odd tile: real m only for col < 13
    float pen = (col >= 13) ? -1.0e30f : 0.0f;

    int swz0 = ((quad       ^ (col & 7)) << 3);
    int swz1 = (((4 + quad) ^ (col & 7)) << 3);

    WAIT_VMCNT(0);                    // staging + A-loads complete
    __builtin_amdgcn_s_barrier();     // one barrier for the whole kernel

    for (int pr = 0; pr < npair; ++pr) {
        int re = (pr * 2) * 16 + col;
        int ro = re + 16;
        half8 B0e = *(const half8*)(lds + re * CC + swz0);
        half8 B1e = *(const half8*)(lds + re * CC + swz1);
        half8 B0o = *(const half8*)(lds + ro * CC + swz0);
        half8 B1o = *(const half8*)(lds + ro * CC + swz1);
        bool dopen = (ms == 4) && (pr == 12);
        #pragma unroll
        for (int qt = 0; qt < 7; ++qt) {
            float4_ z = {0.f, 0.f, 0.f, 0.f};
            float4_ ae = __builtin_amdgcn_mfma_f32_16x16x32_f16(A0[qt], B0e, z, 0, 0, 0);
            ae = __builtin_amdgcn_mfma_f32_16x16x32_f16(A1[qt], B1e, ae, 0, 0, 0);
            float4_ ao = __builtin_amdgcn_mfma_f32_16x16x32_f16(A0[qt], B0o, z, 0, 0, 0);
            ao = __builtin_amdgcn_mfma_f32_16x16x32_f16(A1[qt], B1o, ao, 0, 0, 0);
            if (dopen) { ao.x += pen; ao.y += pen; ao.z += pen; ao.w += pen; }
            ins2(fmaxf(ae.x, ao.x), t0[qt][0], t1[qt][0]);
            ins2(fmaxf(ae.y, ao.y), t0[qt][1], t1[qt][1]);
            ins2(fmaxf(ae.z, ao.z), t0[qt][2], t1[qt][2]);
            ins2(fmaxf(ae.w, ao.w), t0[qt][3], t1[qt][3]);
        }
    }

    // 2-step pair-butterfly (xor 1,2): exact top-2 per 4-col group; 4 writer
    // lanes per 16-col row store float2 -> merge kernel finishes top-3.
    size_t pbase = (size_t)(bn * NSPLIT + ms) * QP;
    int g = col >> 2;                  // 0..3
    bool writer = (col & 3) == 0;
    #pragma unroll
    for (int qt = 0; qt < 7; ++qt) {
        #pragma unroll
        for (int r = 0; r < 4; ++r) {
            float a0 = t0[qt][r], a1 = t1[qt][r];
            #pragma unroll
            for (int s = 1; s <= 2; s <<= 1) {
                float b0 = __shfl_xor(a0, s);
                float b1 = __shfl_xor(a1, s);
                mrgp(b0, b1, a0, a1);
            }
            if (writer) {
                int q = wave * 112 + qt * 16 + quad * 4 + r;
                float2_ v2; v2.x = a0; v2.y = a1;
                partial[(pbase + q) * 4 + g] = v2;
            }
        }
    }
}

// ---- merge: per (bn), each thread owns one query: top-3 of 20 sorted pairs
// (5 splits x 4 col-groups), sum, LDS-reduce over queries ----
__global__ __launch_bounds__(448) void merge_splits(const float2_* __restrict__ partial,
                                                    float* __restrict__ out) {
    __shared__ float red[512];
    int bn = blockIdx.x;
    int q  = threadIdx.x;      // 0..447
    float a0 = -1.0e30f, a1 = -1.0e30f, a2 = -1.0e30f;
    #pragma unroll
    for (int sp = 0; sp < NSPLIT; ++sp) {
        const float4_* p = (const float4_*)(partial + ((size_t)(bn * NSPLIT + sp) * QP + q) * 4);
        float4_ u = p[0];   // groups 0,1
        float4_ w = p[1];   // groups 2,3
        inspair3(u.x, u.y, a0, a1, a2);
        inspair3(u.z, u.w, a0, a1, a2);
        inspair3(w.x, w.y, a0, a1, a2);
        inspair3(w.z, w.w, a0, a1, a2);
    }
    float s = (q < HW) ? (a0 + a1 + a2) : 0.f;
    red[q] = s;
    if (q < 64) red[448 + q] = 0.f;
    __syncthreads();
    #pragma unroll
    for (int stride = 256; stride >= 1; stride >>= 1) {
        if (q < stride && q + stride < 512) red[q] += red[q + stride];
        __syncthreads();
    }
    if (q == 0) out[bn] = red[0];
}

extern "C" void kernel_launch(void* const* d_in, const int* in_sizes, int n_in,
                              void* d_out, int out_size, void* d_ws, size_t ws_size,
                              hipStream_t stream) {
    const float* x1 = (const float*)d_in[0];   // [16,64,21,21]
    const float* x2 = (const float*)d_in[1];   // [10,64,2205]
    float* out = (float*)d_out;                // [16,10]

    _Float16* qn    = (_Float16*)d_ws;                 // 16*448*64 halves (linear)
    _Float16* sn    = qn + (size_t)BB * QP * CC;       // 10*2208*64 halves (swizzled)
    float2_* partial = (float2_*)(sn + (size_t)NCLS * MP * CC);  // 160*5*448*4 float2

    prep<<<BB * 14 + NCLS * 69, 256, 0, stream>>>(x1, x2, qn, sn);
    img2class_mfma<<<BB * NCLS * NSPLIT, 256, 0, stream>>>(qn, sn, partial);
    merge_splits<<<BB * NCLS, 448, 0, stream>>>(partial, out);
}